// Round 7
// baseline (56.059 us; speedup 1.0000x reference)
//
#include <hip/hip_runtime.h>
#include <math.h>

#define B_    16
#define N_    6
#define P_    70000
#define H_    112
#define W_    200
#define HW_   (H_ * W_)
#define BSN_  (B_ * N_)
#define QROWS  28                       // rows per slab (H_/4)
#define QCELLS (QROWS * W_)             // 5600 cells, 22.4 KB LDS
#define NSLAB  4
#define THREADS_ 1024

// ws layout: u32 arena[384 buckets][P_] then int cursors[384]
#define NBUCKET (BSN_ * NSLAB)          // 384
#define ARENA_U32 ((size_t)NBUCKET * P_)
#define WS_NEED ((ARENA_U32 + NBUCKET) * 4)

// ---------- shared math helpers (identical codegen everywhere) ----------

__device__ __forceinline__ float rdot(const float r[4], float x, float y, float z) {
    float s = r[0] * x;
    s = fmaf(r[1], y, s);
    s = fmaf(r[2], z, s);
    return s + r[3];
}

__device__ __forceinline__ float rdot4(float r0, float r1, float r2, float r3,
                                       float x, float y, float z) {
    float s = r0 * x;
    s = fmaf(r1, y, s);
    s = fmaf(r2, z, s);
    return s + r3;
}

// 4x4 inverse via adjugate (matches jnp.linalg.inv bit-for-bit here — absmax
// 0.0 through rounds 1-6)
__device__ __forceinline__ void inv4(const float* m, float* o) {
    float inv[16];
    inv[0]  =  m[5]*m[10]*m[15] - m[5]*m[11]*m[14] - m[9]*m[6]*m[15] + m[9]*m[7]*m[14] + m[13]*m[6]*m[11] - m[13]*m[7]*m[10];
    inv[4]  = -m[4]*m[10]*m[15] + m[4]*m[11]*m[14] + m[8]*m[6]*m[15] - m[8]*m[7]*m[14] - m[12]*m[6]*m[11] + m[12]*m[7]*m[10];
    inv[8]  =  m[4]*m[9]*m[15]  - m[4]*m[11]*m[13] - m[8]*m[5]*m[15] + m[8]*m[7]*m[13] + m[12]*m[5]*m[11] - m[12]*m[7]*m[9];
    inv[12] = -m[4]*m[9]*m[14]  + m[4]*m[10]*m[13] + m[8]*m[5]*m[14] - m[8]*m[6]*m[13] - m[12]*m[5]*m[10] + m[12]*m[6]*m[9];
    inv[1]  = -m[1]*m[10]*m[15] + m[1]*m[11]*m[14] + m[9]*m[2]*m[15] - m[9]*m[3]*m[14] - m[13]*m[2]*m[11] + m[13]*m[3]*m[10];
    inv[5]  =  m[0]*m[10]*m[15] - m[0]*m[11]*m[14] - m[8]*m[2]*m[15] + m[8]*m[3]*m[14] + m[12]*m[2]*m[11] - m[12]*m[3]*m[10];
    inv[9]  = -m[0]*m[9]*m[15]  + m[0]*m[11]*m[13] + m[8]*m[1]*m[15] - m[8]*m[3]*m[13] - m[12]*m[1]*m[11] + m[12]*m[3]*m[9];
    inv[13] =  m[0]*m[9]*m[14]  - m[0]*m[10]*m[13] - m[8]*m[1]*m[14] + m[8]*m[2]*m[13] + m[12]*m[1]*m[10] - m[12]*m[2]*m[9];
    inv[2]  =  m[1]*m[6]*m[15]  - m[1]*m[7]*m[14]  - m[5]*m[2]*m[15] + m[5]*m[3]*m[14] + m[13]*m[2]*m[7]  - m[13]*m[3]*m[6];
    inv[6]  = -m[0]*m[6]*m[15]  + m[0]*m[7]*m[14]  + m[4]*m[2]*m[15] - m[4]*m[3]*m[14] - m[12]*m[2]*m[7]  + m[12]*m[3]*m[6];
    inv[10] =  m[0]*m[5]*m[15]  - m[0]*m[7]*m[13]  - m[4]*m[1]*m[15] + m[4]*m[3]*m[13] + m[12]*m[1]*m[7]  - m[12]*m[3]*m[5];
    inv[14] = -m[0]*m[5]*m[14]  + m[0]*m[6]*m[13]  + m[4]*m[1]*m[14] - m[4]*m[2]*m[13] - m[12]*m[1]*m[6]  + m[12]*m[2]*m[5];
    inv[3]  = -m[1]*m[6]*m[11]  + m[1]*m[7]*m[10]  + m[5]*m[2]*m[11] - m[5]*m[3]*m[10] - m[9]*m[2]*m[7]   + m[9]*m[3]*m[6];
    inv[7]  =  m[0]*m[6]*m[11]  - m[0]*m[7]*m[10]  - m[4]*m[2]*m[11] + m[4]*m[3]*m[10] + m[8]*m[2]*m[7]   - m[8]*m[3]*m[6];
    inv[11] = -m[0]*m[5]*m[11]  + m[0]*m[7]*m[9]   + m[4]*m[1]*m[11] - m[4]*m[3]*m[9]  - m[8]*m[1]*m[7]   + m[8]*m[3]*m[5];
    inv[15] =  m[0]*m[5]*m[10]  - m[0]*m[6]*m[9]   - m[4]*m[1]*m[10] + m[4]*m[2]*m[9]  + m[8]*m[1]*m[6]   - m[8]*m[2]*m[5];
    float det = m[0]*inv[0] + m[1]*inv[4] + m[2]*inv[8] + m[3]*inv[12];
    float rdet = 1.0f / det;
    for (int i = 0; i < 16; ++i) o[i] = inv[i] * rdet;
}

// Per-camera: Einv (rigid inverse) and PFC = scale_intrinsics4(K) @ Einv.
__device__ __forceinline__ void cam_mats(const float* Ein, const float* Kin,
                                         float E2[4], float PFC[3][4]) {
    float Einv[4][4];
    for (int i = 0; i < 3; ++i)
        for (int j = 0; j < 3; ++j)
            Einv[i][j] = Ein[j * 4 + i];          // R^T
    for (int i = 0; i < 3; ++i) {                  // -(R^T t), asc-j fma
        float s = Ein[0 * 4 + i] * Ein[0 * 4 + 3];
        s = fmaf(Ein[1 * 4 + i], Ein[1 * 4 + 3], s);
        s = fmaf(Ein[2 * 4 + i], Ein[2 * 4 + 3], s);
        Einv[i][3] = -s;
    }
    Einv[3][0] = Ein[12]; Einv[3][1] = Ein[13];
    Einv[3][2] = Ein[14]; Einv[3][3] = Ein[15];

    float K4[4][4] = {};
    K4[0][0] = Kin[0] * 0.25f;  K4[0][2] = Kin[2] * 0.25f;
    K4[1][1] = Kin[4] * 0.25f;  K4[1][2] = Kin[5] * 0.25f;
    K4[2][2] = 1.0f;            K4[3][3] = 1.0f;

    for (int i = 0; i < 3; ++i)
        for (int j = 0; j < 4; ++j) {
            float s = K4[i][0] * Einv[0][j];
            s = fmaf(K4[i][1], Einv[1][j], s);
            s = fmaf(K4[i][2], Einv[2][j], s);
            s = fmaf(K4[i][3], Einv[3][j], s);
            PFC[i][j] = s;
        }
    for (int j = 0; j < 4; ++j) E2[j] = Einv[2][j];
}

// ---------- K0: zero the bucket cursors ----------

__global__ __launch_bounds__(NBUCKET) void k_init_cursors(int* __restrict__ cursors) {
    cursors[threadIdx.x] = 0;
}

// ---------- K1: project + bucket append. Block = (b, 1024-pt chunk) ----------
// Each (point,cam) appends entry (ym<<25|xm<<17|p) to bucket (b,cam,slab).
// Ranks via wave ballot-match (slab = 2 bits), per-wave bases via plain LDS,
// one device atomicAdd per (block,bucket): no contended atomics anywhere.

#define K1CH 69                          // ceil(70000/1024)

__global__ __launch_bounds__(THREADS_) void k_bucket(
        const float4* __restrict__ pc, const float* __restrict__ extr,
        const float* __restrict__ intr, const float* __restrict__ view,
        unsigned int* __restrict__ arena, int* __restrict__ cursors) {
    __shared__ float sM[84];            // 0..11 Vinv rows, 12.. 6x12 PFC
    __shared__ int   cnt[16][24];       // per-wave per-bucket counts
    __shared__ int   wbase[16][24];     // per-wave bases
    __shared__ int   gb[24];            // per-block global bases

    const int b    = blockIdx.x;
    const int t    = threadIdx.x;
    const int lane = t & 63;
    const int w    = t >> 6;

    if (t == 0) {                       // wave 0: Vinv
        float Vi[16];
        inv4(&view[b * 16], Vi);
        for (int k = 0; k < 12; ++k) sM[k] = Vi[k];
    } else if (t >= 64 && t < 64 + N_) {  // wave 1: 6 cameras
        int n = t - 64;
        float E2[4], PFC[3][4];
        cam_mats(&extr[(b * N_ + n) * 16], &intr[(b * N_ + n) * 9], E2, PFC);
        for (int i = 0; i < 3; ++i)
            for (int j = 0; j < 4; ++j) sM[12 + n * 12 + i * 4 + j] = PFC[i][j];
    }
    __syncthreads();

    const int p = blockIdx.y * THREADS_ + t;
    const bool valid = (p < P_);
    float4 pt = make_float4(0.f, 0.f, 0.f, 0.f);
    if (valid) pt = pc[(size_t)b * P_ + p];
    float lx = rdot(&sM[0], pt.x, pt.y, pt.z);
    float ly = rdot(&sM[4], pt.x, pt.y, pt.z);
    float lz = rdot(&sM[8], pt.x, pt.y, pt.z);

    const unsigned long long lt = (1ull << lane) - 1ull;
    int stash[6];                        // (code<<9)|(rank<<3)|slab, static idx

    #pragma unroll
    for (int n = 0; n < 6; ++n) {
        const float* Pm = &sM[12 + n * 12];
        float px = rdot(&Pm[0], lx, ly, lz);
        float py = rdot(&Pm[4], lx, ly, lz);
        float pz = rdot(&Pm[8], lx, ly, lz);
        float denom = fmaxf(pz, 1e-6f);
        float x_ = px / denom;
        float y_ = py / denom;
        int ym = (int)fminf(fmaxf(y_, 0.0f), (float)(H_ - 1));
        int xm = (int)fminf(fmaxf(x_, 0.0f), (float)(W_ - 1));
        int code = (ym << 8) | xm;
        int slab = (ym * 585) >> 14;     // ym/28 for ym in [0,112)
        unsigned long long ACT = __ballot(valid);
        unsigned long long B0  = __ballot(valid && (slab & 1));
        unsigned long long B1  = __ballot(valid && (slab & 2));
        unsigned long long m   = ((slab & 1) ? B0 : ~B0) &
                                 ((slab & 2) ? B1 : ~B1) & ACT;
        int rank = (int)__popcll(m & lt);
        if (lane < 4) {
            unsigned long long ml = ((lane & 1) ? B0 : ~B0) &
                                    ((lane & 2) ? B1 : ~B1) & ACT;
            cnt[w][n * 4 + lane] = (int)__popcll(ml);
        }
        stash[n] = (code << 9) | (rank << 3) | slab;
    }
    __syncthreads();

    if (t < 24) {                        // block prefix over waves + global base
        int s = 0;
        for (int w2 = 0; w2 < 16; ++w2) { wbase[w2][t] = s; s += cnt[w2][t]; }
        gb[t] = atomicAdd(&cursors[b * 24 + t], s);
    }
    __syncthreads();

    if (valid) {
        #pragma unroll
        for (int n = 0; n < 6; ++n) {
            int sv   = stash[n];
            int slab = sv & 7;
            int rank = (sv >> 3) & 63;
            int code = sv >> 9;
            int j    = n * 4 + slab;
            size_t slot = (size_t)((b * N_ + n) * NSLAB + slab) * P_ +
                          (size_t)(gb[j] + wbase[w][j] + rank);
            arena[slot] = ((unsigned int)code << 17) | (unsigned int)p;
        }
    }
}

// ---------- K2: per-bucket scatter + finalize. Block = (b,cam,slab) ----------

__global__ __launch_bounds__(THREADS_) void k_scatfin2(
        const float4* __restrict__ pc, const unsigned int* __restrict__ arena,
        const int* __restrict__ cursors,
        const float* __restrict__ extr, const float* __restrict__ intr,
        const float* __restrict__ view,
        float* __restrict__ out, const int* __restrict__ bev_side_p) {
    __shared__ int   win[QCELLS];       // 22.4 KB
    __shared__ float sM[28];            // 0..11 Vinv, 12..23 PFC, 24..27 E2

    // XCD swizzle: match K1's placement (K1 block id = b + 16*chunk -> XCD b%8)
    const int i   = blockIdx.x;
    const int xcd = i & 7;
    const int j   = i >> 3;             // 0..47
    const int b   = xcd + 8 * (j >= 24 ? 1 : 0);
    const int r   = j % 24;
    const int cam = r >> 2;
    const int q   = r & 3;
    const int m   = b * N_ + cam;
    const int rlo = q * QROWS;
    const int t   = threadIdx.x;

    if (t == 0) {                        // wave 0: Vinv
        float Vi[16];
        inv4(&view[b * 16], Vi);
        for (int k = 0; k < 12; ++k) sM[k] = Vi[k];
    } else if (t == 64) {                // wave 1: this camera
        float E2[4], PFC[3][4];
        cam_mats(&extr[m * 16], &intr[m * 9], E2, PFC);
        for (int ii = 0; ii < 3; ++ii)
            for (int jj = 0; jj < 4; ++jj) sM[12 + ii * 4 + jj] = PFC[ii][jj];
        for (int jj = 0; jj < 4; ++jj) sM[24 + jj] = E2[jj];
    }
    for (int k = t; k < QCELLS; k += THREADS_) win[k] = -1;
    __syncthreads();

    // ---- Phase A: dense scan of this bucket's entries ----
    const unsigned int* seg = arena + (size_t)(m * NSLAB + q) * P_;
    const int cntq = cursors[b * 24 + cam * 4 + q];
    // corner codes for this slab (q 1,2: none; codes are >= 0 so -1 never hits)
    const int ccA = (q == 0) ? 0   : ((q == 3) ? ((111 << 8) | 0)   : -1);
    const int ccB = (q == 0) ? 199 : ((q == 3) ? ((111 << 8) | 199) : -1);
    int cA = -1, cB = -1;

    const int nv = cntq >> 2;            // whole uint4s
    const uint4* seg4 = (const uint4*)seg;
    for (int v = t; v < nv; v += THREADS_) {
        uint4 e4 = seg4[v];
        unsigned int es[4] = {e4.x, e4.y, e4.z, e4.w};
        #pragma unroll
        for (int h = 0; h < 4; ++h) {
            unsigned int e = es[h];
            int code = (int)(e >> 17);
            int p    = (int)(e & 0x1FFFFu);
            if (code == ccA)      cA = max(cA, p);
            else if (code == ccB) cB = max(cB, p);
            else {
                int ym = code >> 8, xm = code & 255;
                atomicMax(&win[(ym - rlo) * W_ + xm], p);
            }
        }
    }
    {   // scalar tail (< 4 entries)
        int k2 = (nv << 2) + t;
        if (k2 < cntq) {
            unsigned int e = seg[k2];
            int code = (int)(e >> 17);
            int p    = (int)(e & 0x1FFFFu);
            if (code == ccA)      cA = max(cA, p);
            else if (code == ccB) cB = max(cB, p);
            else {
                int ym = code >> 8, xm = code & 255;
                atomicMax(&win[(ym - rlo) * W_ + xm], p);
            }
        }
    }
    for (int d = 32; d; d >>= 1) {
        cA = max(cA, __shfl_xor(cA, d));
        cB = max(cB, __shfl_xor(cB, d));
    }
    if ((t & 63) == 0) {
        if (q == 0) {
            if (cA >= 0) atomicMax(&win[0],   cA);
            if (cB >= 0) atomicMax(&win[199], cB);
        } else if (q == 3) {
            if (cA >= 0) atomicMax(&win[(H_ - 1 - rlo) * W_ + 0],   cA);
            if (cB >= 0) atomicMax(&win[(H_ - 1 - rlo) * W_ + 199], cB);
        }
    }
    __syncthreads();

    // ---- Phase B: finalize this block's rows (recompute winners only) ----
    const float bev_half = (float)bev_side_p[0] * 0.5f;   // 100.0
    const float clip_hi  = bev_half - 1.0f;               // 99.0
    const float4* pcb = pc + (size_t)b * P_;
    const int base0 = (m * 2) * HW_ + rlo * W_;
    for (int rr = t; rr < QCELLS; rr += THREADS_) {
        int wv = win[rr];
        float depth = 0.0f, iluv = 0.0f;
        if (wv >= 0) {
            float4 pt = pcb[wv];
            float lx = rdot4(sM[0],  sM[1],  sM[2],  sM[3],  pt.x, pt.y, pt.z);
            float ly = rdot4(sM[4],  sM[5],  sM[6],  sM[7],  pt.x, pt.y, pt.z);
            float lz = rdot4(sM[8],  sM[9],  sM[10], sM[11], pt.x, pt.y, pt.z);
            float z  = rdot4(sM[24], sM[25], sM[26], sM[27], lx, ly, lz);
            float px = rdot4(sM[12], sM[13], sM[14], sM[15], lx, ly, lz);
            float py = rdot4(sM[16], sM[17], sM[18], sM[19], lx, ly, lz);
            float pz = rdot4(sM[20], sM[21], sM[22], sM[23], lx, ly, lz);
            float denom = fmaxf(pz, 1e-6f);
            float x_ = px / denom;
            float y_ = py / denom;
            bool valid = (x_ > -0.5f) && (x_ < (float)W_ - 0.5f) &&
                         (y_ > -0.5f) && (y_ < (float)H_ - 0.5f) && (z > 0.0f);
            if (valid) {
                float d = fminf(fmaxf(pz, 0.0f), clip_hi);     // clip(normalizer,0,99)
                depth = d / bev_half;                           // /100
                float vi = fminf(fmaxf(pt.w, 0.0f), 255.0f);    // clip(ilu,0,255)
                iluv = log1pf(vi) / 5.545177444479562f;         // /log(256) as f32
            }
        }
        out[base0 + rr]       = depth;
        out[base0 + HW_ + rr] = iluv;
    }
}

// ---------- fallback (R3 single-kernel path, if ws too small) ----------

#define HALF_ 56
#define CELLS_ (HALF_ * W_)

__global__ __launch_bounds__(THREADS_) void k_lidar_fused(
        const float4* __restrict__ pc, const float* __restrict__ extr,
        const float* __restrict__ intr, const float* __restrict__ view,
        float* __restrict__ out, const int* __restrict__ bev_side_p) {
    __shared__ int   win[CELLS_];
    __shared__ float sV[4][4];
    __shared__ float sE2[4];
    __shared__ float sP[3][4];

    const int i    = blockIdx.x;
    const int xcd  = i & 7;
    const int s    = i >> 3;
    const int b    = xcd + 8 * (s >= 12 ? 1 : 0);
    const int c12  = s % 12;
    const int m    = b * N_ + (c12 >> 1);
    const int rlo  = (c12 & 1) * HALF_;
    const int t    = threadIdx.x;

    if (t == 0) {
        float Vi[16];
        inv4(&view[b * 16], Vi);
        for (int ii = 0; ii < 4; ++ii)
            for (int jj = 0; jj < 4; ++jj) sV[ii][jj] = Vi[ii * 4 + jj];
    } else if (t == 64) {
        float E2[4], PFC[3][4];
        cam_mats(&extr[m * 16], &intr[m * 9], E2, PFC);
        for (int jj = 0; jj < 4; ++jj) sE2[jj] = E2[jj];
        for (int ii = 0; ii < 3; ++ii)
            for (int jj = 0; jj < 4; ++jj) sP[ii][jj] = PFC[ii][jj];
    }
    for (int k = t; k < CELLS_; k += THREADS_) win[k] = -1;
    __syncthreads();

    const float4* pcb = pc + (size_t)b * P_;
    int c0 = -1, c1 = -1, c2 = -1, c3 = -1;
    for (int p = t; p < P_; p += THREADS_) {
        float4 pt = pcb[p];
        float lx = rdot(sV[0], pt.x, pt.y, pt.z);
        float ly = rdot(sV[1], pt.x, pt.y, pt.z);
        float lz = rdot(sV[2], pt.x, pt.y, pt.z);
        float px = rdot(sP[0], lx, ly, lz);
        float py = rdot(sP[1], lx, ly, lz);
        float pz = rdot(sP[2], lx, ly, lz);
        float denom = fmaxf(pz, 1e-6f);
        float x_ = px / denom;
        float y_ = py / denom;
        int ym = (int)fminf(fmaxf(y_, 0.0f), (float)(H_ - 1));
        int xm = (int)fminf(fmaxf(x_, 0.0f), (float)(W_ - 1));
        bool is_c = (xm == 0 || xm == W_ - 1) && (ym == 0 || ym == H_ - 1);
        int code = ((ym != 0) << 1) | (xm != 0);
        c0 = (is_c && code == 0) ? p : c0;
        c1 = (is_c && code == 1) ? p : c1;
        c2 = (is_c && code == 2) ? p : c2;
        c3 = (is_c && code == 3) ? p : c3;
        int rr = ym - rlo;
        if (!is_c && (unsigned)rr < (unsigned)HALF_)
            atomicMax(&win[rr * W_ + xm], p);
    }
    for (int d = 32; d; d >>= 1) {
        c0 = max(c0, __shfl_xor(c0, d));
        c1 = max(c1, __shfl_xor(c1, d));
        c2 = max(c2, __shfl_xor(c2, d));
        c3 = max(c3, __shfl_xor(c3, d));
    }
    if ((t & 63) == 0) {
        if (rlo == 0) {
            if (c0 >= 0) atomicMax(&win[0],   c0);
            if (c1 >= 0) atomicMax(&win[199], c1);
        } else {
            if (c2 >= 0) atomicMax(&win[(H_ - 1 - rlo) * W_ + 0],   c2);
            if (c3 >= 0) atomicMax(&win[(H_ - 1 - rlo) * W_ + 199], c3);
        }
    }
    __syncthreads();

    const float bev_half = (float)bev_side_p[0] * 0.5f;
    const float clip_hi  = bev_half - 1.0f;
    const int base0 = (m * 2) * HW_ + rlo * W_;
    for (int rr = t; rr < CELLS_; rr += THREADS_) {
        int w = win[rr];
        float depth = 0.0f, iluv = 0.0f;
        if (w >= 0) {
            float4 pt = pcb[w];
            float lx = rdot(sV[0], pt.x, pt.y, pt.z);
            float ly = rdot(sV[1], pt.x, pt.y, pt.z);
            float lz = rdot(sV[2], pt.x, pt.y, pt.z);
            float z  = rdot(sE2,   lx, ly, lz);
            float px = rdot(sP[0], lx, ly, lz);
            float py = rdot(sP[1], lx, ly, lz);
            float pz = rdot(sP[2], lx, ly, lz);
            float denom = fmaxf(pz, 1e-6f);
            float x_ = px / denom;
            float y_ = py / denom;
            bool valid = (x_ > -0.5f) && (x_ < (float)W_ - 0.5f) &&
                         (y_ > -0.5f) && (y_ < (float)H_ - 0.5f) && (z > 0.0f);
            if (valid) {
                float d = fminf(fmaxf(pz, 0.0f), clip_hi);
                depth = d / bev_half;
                float vi = fminf(fmaxf(pt.w, 0.0f), 255.0f);
                iluv = log1pf(vi) / 5.545177444479562f;
            }
        }
        out[base0 + rr]       = depth;
        out[base0 + HW_ + rr] = iluv;
    }
}

// ---------- launch ----------

extern "C" void kernel_launch(void* const* d_in, const int* in_sizes, int n_in,
                              void* d_out, int out_size, void* d_ws, size_t ws_size,
                              hipStream_t stream) {
    const float4* pc  = (const float4*)d_in[0];
    const float* extr = (const float*)d_in[1];
    const float* intr = (const float*)d_in[2];
    const float* view = (const float*)d_in[3];
    const int*   bev  = (const int*)d_in[4];
    float* out = (float*)d_out;

    if (ws_size >= WS_NEED) {
        unsigned int* arena = (unsigned int*)d_ws;
        int* cursors = (int*)(arena + ARENA_U32);
        k_init_cursors<<<dim3(1), dim3(NBUCKET), 0, stream>>>(cursors);
        k_bucket<<<dim3(B_, K1CH), dim3(THREADS_), 0, stream>>>(
            pc, extr, intr, view, arena, cursors);
        k_scatfin2<<<dim3(NBUCKET), dim3(THREADS_), 0, stream>>>(
            pc, arena, cursors, extr, intr, view, out, bev);
    } else {
        k_lidar_fused<<<dim3(BSN_ * 2), dim3(THREADS_), 0, stream>>>(
            pc, extr, intr, view, out, bev);
    }
}

// Round 8
// 46.722 us; speedup vs baseline: 1.1999x; 1.1999x over previous
//
#include <hip/hip_runtime.h>
#include <math.h>

#define B_    16
#define N_    6
#define P_    70000
#define H_    112
#define W_    200
#define HW_   (H_ * W_)
#define BSN_  (B_ * N_)
#define HALF_ 56                       // rows per block (H_/2)
#define CELLS_ (HALF_ * W_)            // 11200 cells, 44.8 KB LDS
#define THREADS_ 1024
#define PMAIN 69632                    // 17 * 4096
#define PTAIL (P_ - PMAIN)             // 368

// ---------- shared math helpers (identical codegen everywhere) ----------

__device__ __forceinline__ float rdot4(float r0, float r1, float r2, float r3,
                                       float x, float y, float z) {
    float s = r0 * x;
    s = fmaf(r1, y, s);
    s = fmaf(r2, z, s);
    return s + r3;
}

// 4x4 inverse via adjugate (matches jnp.linalg.inv bit-for-bit here — absmax
// 0.0 through rounds 1-7)
__device__ __forceinline__ void inv4(const float* m, float* o) {
    float inv[16];
    inv[0]  =  m[5]*m[10]*m[15] - m[5]*m[11]*m[14] - m[9]*m[6]*m[15] + m[9]*m[7]*m[14] + m[13]*m[6]*m[11] - m[13]*m[7]*m[10];
    inv[4]  = -m[4]*m[10]*m[15] + m[4]*m[11]*m[14] + m[8]*m[6]*m[15] - m[8]*m[7]*m[14] - m[12]*m[6]*m[11] + m[12]*m[7]*m[10];
    inv[8]  =  m[4]*m[9]*m[15]  - m[4]*m[11]*m[13] - m[8]*m[5]*m[15] + m[8]*m[7]*m[13] + m[12]*m[5]*m[11] - m[12]*m[7]*m[9];
    inv[12] = -m[4]*m[9]*m[14]  + m[4]*m[10]*m[13] + m[8]*m[5]*m[14] - m[8]*m[6]*m[13] - m[12]*m[5]*m[10] + m[12]*m[6]*m[9];
    inv[1]  = -m[1]*m[10]*m[15] + m[1]*m[11]*m[14] + m[9]*m[2]*m[15] - m[9]*m[3]*m[14] - m[13]*m[2]*m[11] + m[13]*m[3]*m[10];
    inv[5]  =  m[0]*m[10]*m[15] - m[0]*m[11]*m[14] - m[8]*m[2]*m[15] + m[8]*m[3]*m[14] + m[12]*m[2]*m[11] - m[12]*m[3]*m[10];
    inv[9]  = -m[0]*m[9]*m[15]  + m[0]*m[11]*m[13] + m[8]*m[1]*m[15] - m[8]*m[3]*m[13] - m[12]*m[1]*m[11] + m[12]*m[3]*m[9];
    inv[13] =  m[0]*m[9]*m[14]  - m[0]*m[10]*m[13] - m[8]*m[1]*m[14] + m[8]*m[2]*m[13] + m[12]*m[1]*m[10] - m[12]*m[2]*m[9];
    inv[2]  =  m[1]*m[6]*m[15]  - m[1]*m[7]*m[14]  - m[5]*m[2]*m[15] + m[5]*m[3]*m[14] + m[13]*m[2]*m[7]  - m[13]*m[3]*m[6];
    inv[6]  = -m[0]*m[6]*m[15]  + m[0]*m[7]*m[14]  + m[4]*m[2]*m[15] - m[4]*m[3]*m[14] - m[12]*m[2]*m[7]  + m[12]*m[3]*m[6];
    inv[10] =  m[0]*m[5]*m[15]  - m[0]*m[7]*m[13]  - m[4]*m[1]*m[15] + m[4]*m[3]*m[13] + m[12]*m[1]*m[7]  - m[12]*m[3]*m[5];
    inv[14] = -m[0]*m[5]*m[14]  + m[0]*m[6]*m[13]  + m[4]*m[1]*m[14] - m[4]*m[2]*m[13] - m[12]*m[1]*m[6]  + m[12]*m[2]*m[5];
    inv[3]  = -m[1]*m[6]*m[11]  + m[1]*m[7]*m[10]  + m[5]*m[2]*m[11] - m[5]*m[3]*m[10] - m[9]*m[2]*m[7]   + m[9]*m[3]*m[6];
    inv[7]  =  m[0]*m[6]*m[11]  - m[0]*m[7]*m[10]  - m[4]*m[2]*m[11] + m[4]*m[3]*m[10] + m[8]*m[2]*m[7]   - m[8]*m[3]*m[6];
    inv[11] = -m[0]*m[5]*m[11]  + m[0]*m[7]*m[9]   + m[4]*m[1]*m[11] - m[4]*m[3]*m[9]  - m[8]*m[1]*m[7]   + m[8]*m[3]*m[5];
    inv[15] =  m[0]*m[5]*m[10]  - m[0]*m[6]*m[9]   - m[4]*m[1]*m[10] + m[4]*m[2]*m[9]  + m[8]*m[1]*m[6]   - m[8]*m[2]*m[5];
    float det = m[0]*inv[0] + m[1]*inv[4] + m[2]*inv[8] + m[3]*inv[12];
    float rdet = 1.0f / det;
    for (int i = 0; i < 16; ++i) o[i] = inv[i] * rdet;
}

// Per-camera: Einv (rigid inverse) and PFC = scale_intrinsics4(K) @ Einv.
__device__ __forceinline__ void cam_mats(const float* Ein, const float* Kin,
                                         float E2[4], float PFC[3][4]) {
    float Einv[4][4];
    for (int i = 0; i < 3; ++i)
        for (int j = 0; j < 3; ++j)
            Einv[i][j] = Ein[j * 4 + i];          // R^T
    for (int i = 0; i < 3; ++i) {                  // -(R^T t), asc-j fma
        float s = Ein[0 * 4 + i] * Ein[0 * 4 + 3];
        s = fmaf(Ein[1 * 4 + i], Ein[1 * 4 + 3], s);
        s = fmaf(Ein[2 * 4 + i], Ein[2 * 4 + 3], s);
        Einv[i][3] = -s;
    }
    Einv[3][0] = Ein[12]; Einv[3][1] = Ein[13];
    Einv[3][2] = Ein[14]; Einv[3][3] = Ein[15];

    float K4[4][4] = {};
    K4[0][0] = Kin[0] * 0.25f;  K4[0][2] = Kin[2] * 0.25f;
    K4[1][1] = Kin[4] * 0.25f;  K4[1][2] = Kin[5] * 0.25f;
    K4[2][2] = 1.0f;            K4[3][3] = 1.0f;

    for (int i = 0; i < 3; ++i)
        for (int j = 0; j < 4; ++j) {
            float s = K4[i][0] * Einv[0][j];
            s = fmaf(K4[i][1], Einv[1][j], s);
            s = fmaf(K4[i][2], Einv[2][j], s);
            s = fmaf(K4[i][3], Einv[3][j], s);
            PFC[i][j] = s;
        }
    for (int j = 0; j < 4; ++j) E2[j] = Einv[2][j];
}

// ---------- fused kernel: one block per (camera m, row-half) ----------
// Identical to round-3 structure (absmax 0.0, 49 us) EXCEPT phase A runs
// 4 independent point-chains per iteration (ILP), with launch_bounds(,4)
// so the chains live in registers (R3 compiled to VGPR=32 -> serialized
// ~110-cycle dependent chains at only 4 waves/SIMD; that was the stall).

__global__ __launch_bounds__(THREADS_, 4) void k_lidar_ilp(
        const float4* __restrict__ pc, const float* __restrict__ extr,
        const float* __restrict__ intr, const float* __restrict__ view,
        float* __restrict__ out, const int* __restrict__ bev_side_p) {
    __shared__ int   win[CELLS_];      // 44.8 KB
    __shared__ float sM[28];           // 0..11 Vinv, 12..23 PFC, 24..27 E2

    // XCD swizzle: co-locate all 12 blocks of one batch on one XCD.
    const int i    = blockIdx.x;       // 0..191
    const int xcd  = i & 7;
    const int s    = i >> 3;           // 0..23
    const int b    = xcd + 8 * (s >= 12 ? 1 : 0);
    const int c12  = s % 12;
    const int m    = b * N_ + (c12 >> 1);
    const int rlo  = (c12 & 1) * HALF_;
    const int t    = threadIdx.x;

    if (t == 0) {                      // wave 0: Vinv
        float Vi[16];
        inv4(&view[b * 16], Vi);
        for (int k = 0; k < 12; ++k) sM[k] = Vi[k];
    } else if (t == 64) {              // wave 1: this camera
        float E2[4], PFC[3][4];
        cam_mats(&extr[m * 16], &intr[m * 9], E2, PFC);
        for (int ii = 0; ii < 3; ++ii)
            for (int jj = 0; jj < 4; ++jj) sM[12 + ii * 4 + jj] = PFC[ii][jj];
        for (int jj = 0; jj < 4; ++jj) sM[24 + jj] = E2[jj];
    }
    for (int k = t; k < CELLS_; k += THREADS_) win[k] = -1;
    __syncthreads();

    // hoist matrices to registers
    const float V0 = sM[0],  V1 = sM[1],  V2 = sM[2],  V3 = sM[3];
    const float V4 = sM[4],  V5 = sM[5],  V6 = sM[6],  V7 = sM[7];
    const float V8 = sM[8],  V9 = sM[9],  V10 = sM[10], V11 = sM[11];
    const float P00 = sM[12], P01 = sM[13], P02 = sM[14], P03 = sM[15];
    const float P10 = sM[16], P11 = sM[17], P12 = sM[18], P13 = sM[19];
    const float P20 = sM[20], P21 = sM[21], P22 = sM[22], P23 = sM[23];

    const float4* pcb = pc + (size_t)b * P_;
    int c0 = -1, c1 = -1, c2 = -1, c3 = -1;

    // per-point phase-A body (p ascending per thread across calls)
#define PROC(PT, PIDX)                                                        \
    {                                                                         \
        float lx = rdot4(V0, V1, V2,  V3,  (PT).x, (PT).y, (PT).z);           \
        float ly = rdot4(V4, V5, V6,  V7,  (PT).x, (PT).y, (PT).z);           \
        float lz = rdot4(V8, V9, V10, V11, (PT).x, (PT).y, (PT).z);           \
        float px = rdot4(P00, P01, P02, P03, lx, ly, lz);                     \
        float py = rdot4(P10, P11, P12, P13, lx, ly, lz);                     \
        float pz = rdot4(P20, P21, P22, P23, lx, ly, lz);                     \
        float denom = fmaxf(pz, 1e-6f);                                       \
        float x_ = px / denom;                                                \
        float y_ = py / denom;                                                \
        int ym = (int)fminf(fmaxf(y_, 0.0f), (float)(H_ - 1));                \
        int xm = (int)fminf(fmaxf(x_, 0.0f), (float)(W_ - 1));                \
        bool is_c = (xm == 0 || xm == W_ - 1) && (ym == 0 || ym == H_ - 1);   \
        int code = ((ym != 0) << 1) | (xm != 0);                              \
        c0 = (is_c && code == 0) ? (PIDX) : c0;                               \
        c1 = (is_c && code == 1) ? (PIDX) : c1;                               \
        c2 = (is_c && code == 2) ? (PIDX) : c2;                               \
        c3 = (is_c && code == 3) ? (PIDX) : c3;                               \
        int rr = ym - rlo;                                                    \
        if (!is_c && (unsigned)rr < (unsigned)HALF_)                          \
            atomicMax(&win[rr * W_ + xm], (PIDX));                            \
    }

    // ---- Phase A: 17 iterations x 4 independent chains ----
    for (int base = 0; base < PMAIN; base += 4 * THREADS_) {
        float4 q0 = pcb[base + t];
        float4 q1 = pcb[base + t + THREADS_];
        float4 q2 = pcb[base + t + 2 * THREADS_];
        float4 q3 = pcb[base + t + 3 * THREADS_];
        PROC(q0, base + t)
        PROC(q1, base + t + THREADS_)
        PROC(q2, base + t + 2 * THREADS_)
        PROC(q3, base + t + 3 * THREADS_)
    }
    if (t < PTAIL) {                   // tail: points 69632..69999
        float4 q = pcb[PMAIN + t];
        PROC(q, PMAIN + t)
    }
#undef PROC

    // wave-reduce corner maxima, then one atomic per wave per in-slab corner
    for (int d = 32; d; d >>= 1) {
        c0 = max(c0, __shfl_xor(c0, d));
        c1 = max(c1, __shfl_xor(c1, d));
        c2 = max(c2, __shfl_xor(c2, d));
        c3 = max(c3, __shfl_xor(c3, d));
    }
    if ((t & 63) == 0) {
        if (rlo == 0) {                // rows 0..55: corners (0,0),(0,199)
            if (c0 >= 0) atomicMax(&win[0],   c0);
            if (c1 >= 0) atomicMax(&win[199], c1);
        } else {                       // rows 56..111: corners (111,0),(111,199)
            if (c2 >= 0) atomicMax(&win[(H_ - 1 - rlo) * W_ + 0],   c2);
            if (c3 >= 0) atomicMax(&win[(H_ - 1 - rlo) * W_ + 199], c3);
        }
    }
    __syncthreads();

    // ---- Phase B: finalize this block's rows ----
    const float bev_half = (float)bev_side_p[0] * 0.5f;   // 100.0
    const float clip_hi  = bev_half - 1.0f;               // 99.0
    const float E20 = sM[24], E21 = sM[25], E22 = sM[26], E23 = sM[27];
    const int base0 = (m * 2) * HW_ + rlo * W_;
    for (int r = t; r < CELLS_; r += THREADS_) {
        int w = win[r];
        float depth = 0.0f, iluv = 0.0f;
        if (w >= 0) {
            float4 pt = pcb[w];
            float lx = rdot4(V0, V1, V2,  V3,  pt.x, pt.y, pt.z);
            float ly = rdot4(V4, V5, V6,  V7,  pt.x, pt.y, pt.z);
            float lz = rdot4(V8, V9, V10, V11, pt.x, pt.y, pt.z);
            float z  = rdot4(E20, E21, E22, E23, lx, ly, lz);
            float px = rdot4(P00, P01, P02, P03, lx, ly, lz);
            float py = rdot4(P10, P11, P12, P13, lx, ly, lz);
            float pz = rdot4(P20, P21, P22, P23, lx, ly, lz);
            float denom = fmaxf(pz, 1e-6f);
            float x_ = px / denom;
            float y_ = py / denom;
            bool valid = (x_ > -0.5f) && (x_ < (float)W_ - 0.5f) &&
                         (y_ > -0.5f) && (y_ < (float)H_ - 0.5f) && (z > 0.0f);
            if (valid) {
                float d = fminf(fmaxf(pz, 0.0f), clip_hi);     // clip(normalizer,0,99)
                depth = d / bev_half;                           // /100
                float vi = fminf(fmaxf(pt.w, 0.0f), 255.0f);    // clip(ilu,0,255)
                iluv = log1pf(vi) / 5.545177444479562f;         // /log(256) as f32
            }
        }
        out[base0 + r]       = depth;
        out[base0 + HW_ + r] = iluv;
    }
}

// ---------- launch ----------

extern "C" void kernel_launch(void* const* d_in, const int* in_sizes, int n_in,
                              void* d_out, int out_size, void* d_ws, size_t ws_size,
                              hipStream_t stream) {
    const float4* pc  = (const float4*)d_in[0];
    const float* extr = (const float*)d_in[1];
    const float* intr = (const float*)d_in[2];
    const float* view = (const float*)d_in[3];
    const int*   bev  = (const int*)d_in[4];
    float* out = (float*)d_out;

    k_lidar_ilp<<<dim3(BSN_ * 2), dim3(THREADS_), 0, stream>>>(
        pc, extr, intr, view, out, bev);
}